// Round 7
// baseline (382.385 us; speedup 1.0000x reference)
//
#include <hip/hip_runtime.h>
#include <stdint.h>

#define DIM    2048
#define NE     64
#define NTOK   32768
#define BM     32          // tokens per block
#define NTHR   256         // 4 waves = 2 expert-halves x 2 k32-halves
#define BK     64          // k per chunk (one LDS A-tile)
#define NIT    (DIM/BK)    // 32
#define WPLANE (NE*DIM)    // 131072 elems per bf16 plane
#define S      68          // epilogue LDS row stride
#define ABUF   12288       // bytes per A buffer: 32 rows x 3 planes x 128 B

typedef __attribute__((ext_vector_type(8)))  short  short8;   // 8 bf16 (4 VGPRs)
typedef __attribute__((ext_vector_type(16))) float  f32x16;   // 32x32 MFMA C/D

union U4S8 { uint4 u; short8 s; };

// D = (e0 >> 16) | (e1 & 0xffff0000)
__device__ __forceinline__ unsigned pack_hi16(unsigned e0, unsigned e1) {
    return __builtin_amdgcn_perm(e1, e0, 0x07060302u);
}

// Exact 3-way bf16 truncation split of 8 fp32 (x = hi + mid + lo exactly)
__device__ __forceinline__ void split8(const float4& a, const float4& b,
                                       short8& h, short8& m, short8& l) {
    const float f[8] = {a.x, a.y, a.z, a.w, b.x, b.y, b.z, b.w};
    unsigned hb[8], mb[8], lb[8];
#pragma unroll
    for (int j = 0; j < 8; ++j) {
        const unsigned xb = __float_as_uint(f[j]);
        const unsigned th = xb & 0xffff0000u;
        const float    rh = f[j] - __uint_as_float(th);
        const unsigned rb = __float_as_uint(rh);
        const unsigned tm = rb & 0xffff0000u;
        const float    rm = rh - __uint_as_float(tm);
        hb[j] = th; mb[j] = tm; lb[j] = __float_as_uint(rm);
    }
    U4S8 H, M, L;
    H.u = make_uint4(pack_hi16(hb[0],hb[1]), pack_hi16(hb[2],hb[3]),
                     pack_hi16(hb[4],hb[5]), pack_hi16(hb[6],hb[7]));
    M.u = make_uint4(pack_hi16(mb[0],mb[1]), pack_hi16(mb[2],mb[3]),
                     pack_hi16(mb[4],mb[5]), pack_hi16(mb[6],mb[7]));
    L.u = make_uint4(pack_hi16(lb[0],lb[1]), pack_hi16(lb[2],lb[3]),
                     pack_hi16(lb[4],lb[5]), pack_hi16(lb[6],lb[7]));
    h = H.s; m = M.s; l = L.s;
}

// Pre-kernel: W fp32 [64][2048] -> 3 bf16 planes, frag-contiguous layout
// [plane][k16-block][e][16]. A wave's B-frag load is a contiguous 2 KB span.
__global__ void router_wsplit(const float* __restrict__ W, unsigned short* __restrict__ W3)
{
    const int i = blockIdx.x * 256 + threadIdx.x;   // 131072
    const int e = i >> 11, k = i & 2047;
    const float f = W[i];
    const unsigned xb = __float_as_uint(f);
    const unsigned th = xb & 0xffff0000u;
    const float    rh = f - __uint_as_float(th);
    const unsigned rb = __float_as_uint(rh);
    const unsigned tm = rb & 0xffff0000u;
    const float    rm = rh - __uint_as_float(tm);
    const int dst = (k >> 4) * 1024 + e * 16 + (k & 15);
    W3[dst]            = (unsigned short)(th >> 16);
    W3[WPLANE + dst]   = (unsigned short)(tm >> 16);
    W3[2*WPLANE + dst] = (unsigned short)(__float_as_uint(rm) >> 16);
}

#define MFMA(A, B, C) __builtin_amdgcn_mfma_f32_32x32x16_bf16(A, B, C, 0, 0, 0)

__global__ __launch_bounds__(NTHR, 4)
void router_main(const float* __restrict__ x, const unsigned short* __restrict__ W3,
                 float* __restrict__ out_idx, float* __restrict__ out_w,
                 float* __restrict__ gusage)
{
    // A buffer: byte = row*384 + plane*128 + ((q ^ (row&7))*16), q = k8-chunk 0..7.
    // Write phase (8 lanes = 1 row x 8 chunks) and read phase (8 rows, fixed q,
    // XOR spans 8 groups) are both bank-conflict-free.
    __shared__ __align__(16) unsigned char smem[2 * ABUF];

    const int tid  = threadIdx.x;
    const int w    = tid >> 6;     // 0..3
    const int ln   = tid & 63;
    const int wn   = w & 1;        // expert half: e in [wn*32, wn*32+32)
    const int wkk  = w >> 1;       // k32-half within BK chunk (0..1)
    const int tok0 = blockIdx.x * BM;
    const int arow = ln & 31;      // fragment row (token / expert)
    const int kh   = ln >> 5;      // k sub-offset: +8*kh

    // ---- x staging: thread covers row xr=tid>>3 (0..31), chunk xq=tid&7 (32 B) ----
    const int xr = tid >> 3, xq = tid & 7;
    const float* xp = x + (size_t)(tok0 + xr) * DIM + xq * 8;
    const uint32_t awb = (uint32_t)(xr * 384 + ((xq ^ (xr & 7)) * 16));

    // ---- B frag byte offsets for kb=0,1 (k16 blocks wkk*2+kb); +8192 B per kt ----
    uint32_t bvo[2];
#pragma unroll
    for (int kb = 0; kb < 2; ++kb)
        bvo[kb] = (uint32_t)((((wkk*2 + kb) * 1024) + wn * 512 + arow * 16 + kh * 8) * 2);

    // ---- A frag LDS byte offsets for kb=0,1 (plane via +128/+256 immediates) ----
    uint32_t arb[2];
#pragma unroll
    for (int kb = 0; kb < 2; ++kb) {
        const int q = wkk * 4 + kb * 2 + kh;        // k8-chunk 0..7
        arb[kb] = (uint32_t)(arow * 384 + ((q ^ (arow & 7)) * 16));
    }

    f32x16 acc;
#pragma unroll
    for (int r = 0; r < 16; ++r) acc[r] = 0.f;

    // ---- preheader: stage kt=0 A, prefetch kt=1 x, load kt=0 B ----
    float4 xa = *(const float4*)(xp);
    float4 xb = *(const float4*)(xp + 4);
    {
        short8 sh, sm, sl;
        split8(xa, xb, sh, sm, sl);
        *(short8*)(smem + awb)       = sh;
        *(short8*)(smem + awb + 128) = sm;
        *(short8*)(smem + awb + 256) = sl;
    }
    xa = *(const float4*)(xp + BK);
    xb = *(const float4*)(xp + BK + 4);
    U4S8 b[2][3];
#pragma unroll
    for (int kb = 0; kb < 2; ++kb)
#pragma unroll
        for (int p = 0; p < 3; ++p)
            b[kb][p].u = *(const uint4*)((const unsigned char*)W3 + bvo[kb] + p * (2*WPLANE));
    __syncthreads();

#pragma unroll 2
    for (int kt = 0; kt < NIT; ++kt) {
        const uint32_t cb = (uint32_t)(kt & 1) * ABUF;
        const uint32_t nb = ABUF - cb;

        // EARLY global issues: max distance to this kt's barrier vmcnt drain
        float4 na, nc;
        if (kt + 2 < NIT) {
            na = *(const float4*)(xp + (kt + 2) * BK);
            nc = *(const float4*)(xp + (kt + 2) * BK + 4);
        }
        U4S8 n[2][3];
        if (kt + 1 < NIT) {
            const uint32_t off = (uint32_t)(kt + 1) * 8192;
#pragma unroll
            for (int kb = 0; kb < 2; ++kb)
#pragma unroll
                for (int p = 0; p < 3; ++p)
                    n[kb][p].u = *(const uint4*)((const unsigned char*)W3 + bvo[kb] + off + p * (2*WPLANE));
        }

        // split x(kt+1) -> next buffer
        if (kt + 1 < NIT) {
            short8 sh, sm, sl;
            split8(xa, xb, sh, sm, sl);
            *(short8*)(smem + nb + awb)       = sh;
            *(short8*)(smem + nb + awb + 128) = sm;
            *(short8*)(smem + nb + awb + 256) = sl;
        }

        // compute kt from current buffer: per kb 3 ds_read_b128 + 6 MFMA
#pragma unroll
        for (int kb = 0; kb < 2; ++kb) {
            const unsigned char* base = smem + cb + arb[kb];
            const short8 ah = *(const short8*)(base);
            const short8 am = *(const short8*)(base + 128);
            const short8 al = *(const short8*)(base + 256);
            acc = MFMA(ah, b[kb][0].s, acc);
            acc = MFMA(am, b[kb][0].s, acc);
            acc = MFMA(al, b[kb][0].s, acc);
            acc = MFMA(ah, b[kb][1].s, acc);
            acc = MFMA(am, b[kb][1].s, acc);
            acc = MFMA(ah, b[kb][2].s, acc);
        }
        xa = na; xb = nc;
#pragma unroll
        for (int kb = 0; kb < 2; ++kb)
#pragma unroll
            for (int p = 0; p < 3; ++p) b[kb][p] = n[kb][p];
        __syncthreads();   // A(kt+1) writes visible; cb reusable next iter
    }

    // ---- epilogue: overlay LDS; reduce 2 k-halves; top-2 + softmax + usage ----
    float* ps  = (float*)smem;                 // [32][S] = 8704 B
    float* mxa = (float*)(smem + 8704);        // [32]
    float* zia = (float*)(smem + 8832);        // [32]
    float* usa = (float*)(smem + 8960);        // [4][64]

    for (int pass = 0; pass < 2; ++pass) {
        if (wkk == pass) {
#pragma unroll
            for (int r = 0; r < 16; ++r) {
                const int t = (r & 3) + 8*(r >> 2) + 4*kh;   // C/D layout (m74/m101)
                const int e = wn*32 + arow;
                if (pass == 0) ps[t*S + e]  = acc[r];
                else           ps[t*S + e] += acc[r];
            }
        }
        __syncthreads();
    }

    if (tid < BM) {
        const int t = tid;
        float v1 = -3.4e38f, v2 = -3.4e38f;
        int   i1 = 0, i2 = 0;
        for (int e = 0; e < NE; ++e) {
            float s = ps[t*S + e];
            if (s > v1)      { v2 = v1; i2 = i1; v1 = s; i1 = e; }  // strict >: lowest index wins ties
            else if (s > v2) { v2 = s;  i2 = e; }
        }
        float z = 0.f;
        for (int e = 0; e < NE; ++e) z += __expf(ps[t*S + e] - v1);
        mxa[t] = v1;
        zia[t] = 1.f / z;

        const int gt = tok0 + t;
        out_idx[gt*2 + 0] = (float)i1;
        out_idx[gt*2 + 1] = (float)i2;
        float e21 = __expf(v2 - v1);
        float w1  = 1.f / (1.f + e21);
        out_w[gt*2 + 0] = w1;
        out_w[gt*2 + 1] = e21 * w1;
    }
    __syncthreads();

    {   // per-expert usage partials: thread (c,e) sums 8 tokens
        const int e = tid & 63;
        const int c = tid >> 6;
        float u = 0.f;
        for (int t = c*8; t < c*8 + 8; ++t)
            u += __expf(ps[t*S + e] - mxa[t]) * zia[t];
        usa[c*64 + e] = u;
    }
    __syncthreads();
    if (tid < NE) {
        float u = 0.f;
#pragma unroll
        for (int c = 0; c < 4; ++c) u += usa[c*64 + tid];
        atomicAdd(&gusage[tid], u);
    }
}

__global__ void router_finalize(const float* __restrict__ gusage, float* __restrict__ out_aux)
{
    const int e = threadIdx.x;                 // 64 threads = 1 wave
    float u = gusage[e] * (1.0f / (float)NTOK);
    float s = u * u;
#pragma unroll
    for (int off = 32; off > 0; off >>= 1)
        s += __shfl_down(s, off, 64);
    if (e == 0) out_aux[0] = (float)NE * s;
}

extern "C" void kernel_launch(void* const* d_in, const int* in_sizes, int n_in,
                              void* d_out, int out_size, void* d_ws, size_t ws_size,
                              hipStream_t stream)
{
    const float* x = (const float*)d_in[0];
    const float* W = (const float*)d_in[1];
    float* out     = (float*)d_out;
    float* out_idx = out;                 // [4,8192,2] as float
    float* out_w   = out + NTOK * 2;      // [4,8192,2]
    float* out_aux = out + NTOK * 4;      // scalar

    unsigned short* W3 = (unsigned short*)d_ws;   // 3 planes x 128K bf16 = 768 KB
    float* gusage = (float*)((char*)d_ws + 3 * WPLANE * sizeof(unsigned short));

    hipMemsetAsync(gusage, 0, NE * sizeof(float), stream);
    hipLaunchKernelGGL(router_wsplit, dim3(WPLANE / 256), dim3(256), 0, stream, W, W3);
    hipLaunchKernelGGL(router_main, dim3(NTOK / BM), dim3(NTHR), 0, stream,
                       x, W3, out_idx, out_w, gusage);
    hipLaunchKernelGGL(router_finalize, dim3(1), dim3(NE), 0, stream, gusage, out_aux);
}